// Round 10
// baseline (115.694 us; speedup 1.0000x reference)
//
#include <hip/hip_runtime.h>

#define NT 512

constexpr int L0 = 8192;
constexpr int N1 = 4099;   // (8192+7)>>1
constexpr int N2 = 2053;   // (4099+7)>>1
constexpr int N3 = 1030;   // (2053+7)>>1
constexpr int N4 = 518;    // (1030+7)>>1
constexpr int ROW_OUT = N4 + N4 + N3 + N2 + N1;  // 8218
constexpr int OFF_A4 = 0;
constexpr int OFF_D4 = 518;
constexpr int OFF_D3 = 1036;
constexpr int OFF_D2 = 2066;
constexpr int OFF_D1 = 4119;

// Halo SoA stride (slots per coefficient lane).
constexpr int HS = 520;

// Nontemporal stores are the measured winner (R7 27.5us vs plain 31.3us —
// output is never re-read; bypassing L2 avoids backpressure on the read
// stream). This round additionally ALIGNS every nt vector store:
//   cD1 f4 at c=8t+1 -> float index 4120+8t  == 0 mod 4 (16B aligned)
//   cD2 f4 at c=4t+2 -> float index 2068+4t  == 0 mod 4 (16B aligned)
// boundary element passed to left neighbor via __shfl_down (intra-wave).
typedef float f4a __attribute__((ext_vector_type(4), aligned(16)));
typedef float f2a __attribute__((ext_vector_type(2), aligned(8)));

// lo[i] = sum_j GLO[j] * xsym(2i-6+j)   (GLO = pywt db4 rec_lo = dec_lo reversed)
constexpr float GLO[8] = {
    0.23037781330885523f,  0.7148465705525415f,   0.6308807679295904f,
   -0.02798376941698385f, -0.18703481171888114f,  0.030841381835986965f,
    0.032883011666982945f, -0.010597401784997278f };
// hi[i] = sum_j GHI[j] * xsym(2i-6+j)
constexpr float GHI[8] = {
   -0.010597401784997278f, -0.032883011666982945f, 0.030841381835986965f,
    0.18703481171888114f,  -0.02798376941698385f,  -0.6308807679295904f,
    0.7148465705525415f,   -0.23037781330885523f };

// Round-7 register cascade (verified bit-exact, best measured) + aligned
// nontemporal stores. One row per block, 3 barriers. Do NOT hold extra
// state across phases (R8's launch-bounds spill lesson).
__global__ __launch_bounds__(NT, 8) void wavedec4_db4(const float* __restrict__ x,
                                                      float* __restrict__ out)
{
    __shared__ float hA[8 * HS];   // 16640 B : cA1 SoA, later cA3 [g&1][g>>1]
    __shared__ float hB[4 * HS];   //  8320 B : cA2 SoA [m*HS + t]
    const int t = threadIdx.x;
    const int lane = t & 63;
    const float* __restrict__ xr = x + blockIdx.x * (size_t)L0;
    float* __restrict__ outr = out + blockIdx.x * (size_t)ROW_OUT;

    // ---- load x window [16t-8, 16t+16) into registers, all loads up front ----
    float xw[24];
    if (t > 0) {
        const float4* p = (const float4*)(xr + 16 * t - 8);
        float4 v0 = p[0], v1 = p[1], v2 = p[2], v3 = p[3], v4 = p[4], v5 = p[5];
        xw[0] = v0.x;  xw[1] = v0.y;  xw[2] = v0.z;  xw[3] = v0.w;
        xw[4] = v1.x;  xw[5] = v1.y;  xw[6] = v1.z;  xw[7] = v1.w;
        xw[8] = v2.x;  xw[9] = v2.y;  xw[10] = v2.z; xw[11] = v2.w;
        xw[12] = v3.x; xw[13] = v3.y; xw[14] = v3.z; xw[15] = v3.w;
        xw[16] = v4.x; xw[17] = v4.y; xw[18] = v4.z; xw[19] = v4.w;
        xw[20] = v5.x; xw[21] = v5.y; xw[22] = v5.z; xw[23] = v5.w;
    } else {
        const float4* p = (const float4*)xr;
        float4 v0 = p[0], v1 = p[1], v2 = p[2], v3 = p[3];
        xw[8] = v0.x;  xw[9] = v0.y;  xw[10] = v0.z; xw[11] = v0.w;
        xw[12] = v1.x; xw[13] = v1.y; xw[14] = v1.z; xw[15] = v1.w;
        xw[16] = v2.x; xw[17] = v2.y; xw[18] = v2.z; xw[19] = v2.w;
        xw[20] = v3.x; xw[21] = v3.y; xw[22] = v3.z; xw[23] = v3.w;
#pragma unroll
        for (int k = 0; k < 8; ++k) xw[k] = xw[15 - k];   // xsym(k-8) = x[7-k]
    }

    // ---- L1: outputs i = 8t+m, taps xw[2m+2+j] ----
    float lo1[8], hi1[8];
#pragma unroll
    for (int m = 0; m < 8; ++m) {
        float l = 0.f, h = 0.f;
#pragma unroll
        for (int j = 0; j < 8; ++j) {
            float v = xw[2 * m + 2 + j];
            l = fmaf(GLO[j], v, l);
            h = fmaf(GHI[j], v, h);
        }
        lo1[m] = l;
        hi1[m] = h;
        hA[m * HS + t] = l;
    }
    {   // aligned coalesced cD1 stores: lane holds cD1[8t..8t+7].
        // [8t+1..8t+4] and [8t+5..8t+8] are 16B-aligned; cD1[8t+8] comes
        // from the right neighbor via shfl; cD1[8t] is stored by the left
        // neighbor (lane 0 stores its own; lane 63 lacks a neighbor value
        // and finishes with f2 + scalar).
        float nb = __shfl_down(hi1[0], 1);
        f4a a = { hi1[1], hi1[2], hi1[3], hi1[4] };
        __builtin_nontemporal_store(a, (f4a*)(outr + OFF_D1 + 8 * t + 1));
        if (lane < 63) {
            f4a b = { hi1[5], hi1[6], hi1[7], nb };
            __builtin_nontemporal_store(b, (f4a*)(outr + OFF_D1 + 8 * t + 5));
        } else {
            f2a b = { hi1[5], hi1[6] };
            __builtin_nontemporal_store(b, (f2a*)(outr + OFF_D1 + 8 * t + 5));
            __builtin_nontemporal_store(hi1[7], outr + OFF_D1 + 8 * t + 7);
        }
        if (lane == 0) __builtin_nontemporal_store(hi1[0], outr + OFF_D1 + 8 * t);
    }
    if (t == NT - 1) {   // L1 tail i = 4096..4098, entirely from xw registers
#pragma unroll
        for (int e = 0; e < 3; ++e) {
            const int i = 4096 + e;
            float l = 0.f, h = 0.f;
#pragma unroll
            for (int j = 0; j < 8; ++j) {
                int q = 2 * i - 6 + j;                       // 8186..8202
                int idx = ((q <= 8191) ? q : (16383 - q)) - 8168;
                float v = xw[idx];
                l = fmaf(GLO[j], v, l);
                h = fmaf(GHI[j], v, h);
            }
            __builtin_nontemporal_store(h, outr + OFF_D1 + i);
            hA[(i & 7) * HS + (i >> 3)] = l;
        }
    }
    __syncthreads();

    // ---- L2: outputs j = 4t+m, taps w2[2m+j'] where w2[k] = cA1[8t-6+k] ----
    float w2[14];
#pragma unroll
    for (int k = 0; k < 6; ++k) {
        int g = 8 * t - 6 + k;
        if (g < 0) g = -1 - g;                 // front reflection (t=0 only)
        w2[k] = hA[(g & 7) * HS + (g >> 3)];
    }
#pragma unroll
    for (int m = 0; m < 8; ++m) w2[6 + m] = lo1[m];
    float lo2[4], hi2[4];
#pragma unroll
    for (int m = 0; m < 4; ++m) {
        float l = 0.f, h = 0.f;
#pragma unroll
        for (int j = 0; j < 8; ++j) {
            float v = w2[2 * m + j];
            l = fmaf(GLO[j], v, l);
            h = fmaf(GHI[j], v, h);
        }
        lo2[m] = l;
        hi2[m] = h;
        hB[m * HS + t] = l;
    }
    {   // aligned coalesced cD2 store: lane holds cD2[4t..4t+3].
        // [4t+2..4t+5] is 16B-aligned; cD2[4t+4],[4t+5] via shfl from the
        // right neighbor; cD2[4t],[4t+1] stored by the left neighbor
        // (lane 0 stores its own pair; lane 63 stores only its f2).
        float n0 = __shfl_down(hi2[0], 1);
        float n1 = __shfl_down(hi2[1], 1);
        if (lane < 63) {
            f4a a = { hi2[2], hi2[3], n0, n1 };
            __builtin_nontemporal_store(a, (f4a*)(outr + OFF_D2 + 4 * t + 2));
        } else {
            f2a a = { hi2[2], hi2[3] };
            __builtin_nontemporal_store(a, (f2a*)(outr + OFF_D2 + 4 * t + 2));
        }
        if (lane == 0) {
            f2a a = { hi2[0], hi2[1] };
            __builtin_nontemporal_store(a, (f2a*)(outr + OFF_D2 + 4 * t));
        }
    }
    if (t < 5) {    // L2 tail: j = 2048..2052 from published cA1 (+tail reflection)
        const int jj = 2048 + t;
        float l = 0.f, h = 0.f;
#pragma unroll
        for (int j = 0; j < 8; ++j) {
            int g = 2 * jj - 6 + j;
            if (g > 4098) g = 8197 - g;        // reflect at N1
            float v = hA[(g & 7) * HS + (g >> 3)];
            l = fmaf(GLO[j], v, l);
            h = fmaf(GHI[j], v, h);
        }
        __builtin_nontemporal_store(h, outr + OFF_D2 + jj);
        hB[(jj & 3) * HS + (jj >> 2)] = l;
    }
    __syncthreads();

    // ---- L3: outputs j = 2t+m, taps w3[2m+j'] where w3[k] = cA2[4t-6+k] ----
    float w3[10];
#pragma unroll
    for (int k = 0; k < 6; ++k) {
        int g = 4 * t - 6 + k;
        if (g < 0) g = -1 - g;
        w3[k] = hB[(g & 3) * HS + (g >> 2)];
    }
#pragma unroll
    for (int m = 0; m < 4; ++m) w3[6 + m] = lo2[m];
    float lo3[2], hi3[2];
#pragma unroll
    for (int m = 0; m < 2; ++m) {
        float l = 0.f, h = 0.f;
#pragma unroll
        for (int j = 0; j < 8; ++j) {
            float v = w3[2 * m + j];
            l = fmaf(GLO[j], v, l);
            h = fmaf(GHI[j], v, h);
        }
        lo3[m] = l;
        hi3[m] = h;
        hA[m * HS + t] = l;                    // cA3 pair view: (2t+m)&1=m, >>1=t
    }
    {   // cD3 store: float index 1036+2t is even -> naturally 8B-aligned
        f2a a = { hi3[0], hi3[1] };
        __builtin_nontemporal_store(a, (f2a*)(outr + OFF_D3 + 2 * t));
    }
    if (t < 6) {    // L3 tail: j = 1024..1029 from published cA2 (+reflection)
        const int jj = 1024 + t;
        float l = 0.f, h = 0.f;
#pragma unroll
        for (int j = 0; j < 8; ++j) {
            int g = 2 * jj - 6 + j;
            if (g > 2052) g = 4105 - g;        // reflect at N2
            float v = hB[(g & 3) * HS + (g >> 2)];
            l = fmaf(GLO[j], v, l);
            h = fmaf(GHI[j], v, h);
        }
        __builtin_nontemporal_store(h, outr + OFF_D3 + jj);
        hA[(jj & 1) * HS + (jj >> 1)] = l;
    }
    __syncthreads();

    // ---- L4: output j = t, taps w4[j'] where w4[k] = cA3[2t-6+k] ----
    float w4[8];
#pragma unroll
    for (int k = 0; k < 6; ++k) {
        int g = 2 * t - 6 + k;
        if (g < 0) g = -1 - g;
        w4[k] = hA[(g & 1) * HS + (g >> 1)];
    }
    w4[6] = lo3[0];
    w4[7] = lo3[1];
    {
        float l = 0.f, h = 0.f;
#pragma unroll
        for (int j = 0; j < 8; ++j) {
            float v = w4[j];
            l = fmaf(GLO[j], v, l);
            h = fmaf(GHI[j], v, h);
        }
        __builtin_nontemporal_store(l, outr + OFF_A4 + t);   // lane-consecutive
        __builtin_nontemporal_store(h, outr + OFF_D4 + t);
    }
    if (t < 6) {    // L4 tail: j = 512..517 from published cA3 (+reflection)
        const int jj = 512 + t;
        float l = 0.f, h = 0.f;
#pragma unroll
        for (int j = 0; j < 8; ++j) {
            int g = 2 * jj - 6 + j;
            if (g > 1029) g = 2059 - g;        // reflect at N3
            float v = hA[(g & 1) * HS + (g >> 1)];
            l = fmaf(GLO[j], v, l);
            h = fmaf(GHI[j], v, h);
        }
        __builtin_nontemporal_store(l, outr + OFF_A4 + jj);
        __builtin_nontemporal_store(h, outr + OFF_D4 + jj);
    }
}

extern "C" void kernel_launch(void* const* d_in, const int* in_sizes, int n_in,
                              void* d_out, int out_size, void* d_ws, size_t ws_size,
                              hipStream_t stream) {
    const float* x = (const float*)d_in[0];
    float* out = (float*)d_out;
    const int rows = in_sizes[0] / L0;  // 64*32 = 2048
    wavedec4_db4<<<dim3(rows), dim3(NT), 0, stream>>>(x, out);
}

// Round 11
// 112.649 us; speedup vs baseline: 1.0270x; 1.0270x over previous
//
#include <hip/hip_runtime.h>

#define NT 512

constexpr int L0 = 8192;
constexpr int N1 = 4099;   // (8192+7)>>1
constexpr int N2 = 2053;   // (4099+7)>>1
constexpr int N3 = 1030;   // (2053+7)>>1
constexpr int N4 = 518;    // (1030+7)>>1
constexpr int ROW_OUT = N4 + N4 + N3 + N2 + N1;  // 8218
constexpr int OFF_A4 = 0;
constexpr int OFF_D4 = 518;
constexpr int OFF_D3 = 1036;
constexpr int OFF_D2 = 2066;
constexpr int OFF_D1 = 4119;

// Halo SoA stride (slots per coefficient lane).
constexpr int HS = 520;

// 4-byte-aligned vector types: out-row offsets (4119+8t etc.) are only
// dword-aligned, AND the row stride 8218 == 2 (mod 4) makes alignment
// alternate with row parity — so 4B-aligned nt vector stores are the
// best achievable (R10's "aligned" variant regressed: +16MB writes from
// parity misalignment + divergent store overhead).
typedef float f4u __attribute__((ext_vector_type(4), aligned(4)));
typedef float f2u __attribute__((ext_vector_type(2), aligned(4)));

// lo[i] = sum_j GLO[j] * xsym(2i-6+j)   (GLO = pywt db4 rec_lo = dec_lo reversed)
constexpr float GLO[8] = {
    0.23037781330885523f,  0.7148465705525415f,   0.6308807679295904f,
   -0.02798376941698385f, -0.18703481171888114f,  0.030841381835986965f,
    0.032883011666982945f, -0.010597401784997278f };
// hi[i] = sum_j GHI[j] * xsym(2i-6+j)
constexpr float GHI[8] = {
   -0.010597401784997278f, -0.032883011666982945f, 0.030841381835986965f,
    0.18703481171888114f,  -0.02798376941698385f,  -0.6308807679295904f,
    0.7148465705525415f,   -0.23037781330885523f };

// Round-7 register cascade — the measured optimum of this session
// (27.5us steady kernel; dur_us 110.7):
//  - one row per 512-thread block, all x loaded to registers up front
//  - 4 levels in-block, cA handoff via LDS SoA (conflict-free), 3 barriers
//  - each lane's cD outputs are CONSECUTIVE -> per-lane float4/float2
//    nontemporal stores (wave covers a dense 1KB run; nt bypasses L2,
//    which measured 4us faster than plain stores despite +6MB partial
//    sectors from the odd base offset)
//  - no cross-phase register state beyond lo1/lo2/lo3 (R8 spill lesson)
__global__ __launch_bounds__(NT, 8) void wavedec4_db4(const float* __restrict__ x,
                                                      float* __restrict__ out)
{
    __shared__ float hA[8 * HS];   // 16640 B : cA1 SoA, later cA3 [g&1][g>>1]
    __shared__ float hB[4 * HS];   //  8320 B : cA2 SoA [m*HS + t]
    const int t = threadIdx.x;
    const float* __restrict__ xr = x + blockIdx.x * (size_t)L0;
    float* __restrict__ outr = out + blockIdx.x * (size_t)ROW_OUT;

    // ---- load x window [16t-8, 16t+16) into registers, all loads up front ----
    float xw[24];
    if (t > 0) {
        const float4* p = (const float4*)(xr + 16 * t - 8);
        float4 v0 = p[0], v1 = p[1], v2 = p[2], v3 = p[3], v4 = p[4], v5 = p[5];
        xw[0] = v0.x;  xw[1] = v0.y;  xw[2] = v0.z;  xw[3] = v0.w;
        xw[4] = v1.x;  xw[5] = v1.y;  xw[6] = v1.z;  xw[7] = v1.w;
        xw[8] = v2.x;  xw[9] = v2.y;  xw[10] = v2.z; xw[11] = v2.w;
        xw[12] = v3.x; xw[13] = v3.y; xw[14] = v3.z; xw[15] = v3.w;
        xw[16] = v4.x; xw[17] = v4.y; xw[18] = v4.z; xw[19] = v4.w;
        xw[20] = v5.x; xw[21] = v5.y; xw[22] = v5.z; xw[23] = v5.w;
    } else {
        const float4* p = (const float4*)xr;
        float4 v0 = p[0], v1 = p[1], v2 = p[2], v3 = p[3];
        xw[8] = v0.x;  xw[9] = v0.y;  xw[10] = v0.z; xw[11] = v0.w;
        xw[12] = v1.x; xw[13] = v1.y; xw[14] = v1.z; xw[15] = v1.w;
        xw[16] = v2.x; xw[17] = v2.y; xw[18] = v2.z; xw[19] = v2.w;
        xw[20] = v3.x; xw[21] = v3.y; xw[22] = v3.z; xw[23] = v3.w;
#pragma unroll
        for (int k = 0; k < 8; ++k) xw[k] = xw[15 - k];   // xsym(k-8) = x[7-k]
    }

    // ---- L1: outputs i = 8t+m, taps xw[2m+2+j] ----
    float lo1[8], hi1[8];
#pragma unroll
    for (int m = 0; m < 8; ++m) {
        float l = 0.f, h = 0.f;
#pragma unroll
        for (int j = 0; j < 8; ++j) {
            float v = xw[2 * m + 2 + j];
            l = fmaf(GLO[j], v, l);
            h = fmaf(GHI[j], v, h);
        }
        lo1[m] = l;
        hi1[m] = h;
        hA[m * HS + t] = l;
    }
    {   // direct coalesced cD1 stores: lane holds cD1[8t..8t+7]
        f4u a = { hi1[0], hi1[1], hi1[2], hi1[3] };
        f4u b = { hi1[4], hi1[5], hi1[6], hi1[7] };
        __builtin_nontemporal_store(a, (f4u*)(outr + OFF_D1 + 8 * t));
        __builtin_nontemporal_store(b, (f4u*)(outr + OFF_D1 + 8 * t + 4));
    }
    if (t == NT - 1) {   // L1 tail i = 4096..4098, entirely from xw registers
#pragma unroll
        for (int e = 0; e < 3; ++e) {
            const int i = 4096 + e;
            float l = 0.f, h = 0.f;
#pragma unroll
            for (int j = 0; j < 8; ++j) {
                int q = 2 * i - 6 + j;                       // 8186..8202
                int idx = ((q <= 8191) ? q : (16383 - q)) - 8168;
                float v = xw[idx];
                l = fmaf(GLO[j], v, l);
                h = fmaf(GHI[j], v, h);
            }
            __builtin_nontemporal_store(h, outr + OFF_D1 + i);
            hA[(i & 7) * HS + (i >> 3)] = l;
        }
    }
    __syncthreads();

    // ---- L2: outputs j = 4t+m, taps w2[2m+j'] where w2[k] = cA1[8t-6+k] ----
    float w2[14];
#pragma unroll
    for (int k = 0; k < 6; ++k) {
        int g = 8 * t - 6 + k;
        if (g < 0) g = -1 - g;                 // front reflection (t=0 only)
        w2[k] = hA[(g & 7) * HS + (g >> 3)];
    }
#pragma unroll
    for (int m = 0; m < 8; ++m) w2[6 + m] = lo1[m];
    float lo2[4], hi2[4];
#pragma unroll
    for (int m = 0; m < 4; ++m) {
        float l = 0.f, h = 0.f;
#pragma unroll
        for (int j = 0; j < 8; ++j) {
            float v = w2[2 * m + j];
            l = fmaf(GLO[j], v, l);
            h = fmaf(GHI[j], v, h);
        }
        lo2[m] = l;
        hi2[m] = h;
        hB[m * HS + t] = l;
    }
    {   // direct coalesced cD2 store: lane holds cD2[4t..4t+3]
        f4u a = { hi2[0], hi2[1], hi2[2], hi2[3] };
        __builtin_nontemporal_store(a, (f4u*)(outr + OFF_D2 + 4 * t));
    }
    if (t < 5) {    // L2 tail: j = 2048..2052 from published cA1 (+tail reflection)
        const int jj = 2048 + t;
        float l = 0.f, h = 0.f;
#pragma unroll
        for (int j = 0; j < 8; ++j) {
            int g = 2 * jj - 6 + j;
            if (g > 4098) g = 8197 - g;        // reflect at N1
            float v = hA[(g & 7) * HS + (g >> 3)];
            l = fmaf(GLO[j], v, l);
            h = fmaf(GHI[j], v, h);
        }
        __builtin_nontemporal_store(h, outr + OFF_D2 + jj);
        hB[(jj & 3) * HS + (jj >> 2)] = l;
    }
    __syncthreads();

    // ---- L3: outputs j = 2t+m, taps w3[2m+j'] where w3[k] = cA2[4t-6+k] ----
    float w3[10];
#pragma unroll
    for (int k = 0; k < 6; ++k) {
        int g = 4 * t - 6 + k;
        if (g < 0) g = -1 - g;
        w3[k] = hB[(g & 3) * HS + (g >> 2)];
    }
#pragma unroll
    for (int m = 0; m < 4; ++m) w3[6 + m] = lo2[m];
    float lo3[2], hi3[2];
#pragma unroll
    for (int m = 0; m < 2; ++m) {
        float l = 0.f, h = 0.f;
#pragma unroll
        for (int j = 0; j < 8; ++j) {
            float v = w3[2 * m + j];
            l = fmaf(GLO[j], v, l);
            h = fmaf(GHI[j], v, h);
        }
        lo3[m] = l;
        hi3[m] = h;
        hA[m * HS + t] = l;                    // cA3 pair view: (2t+m)&1=m, >>1=t
    }
    {   // direct coalesced cD3 store: lane holds cD3[2t..2t+1]
        f2u a = { hi3[0], hi3[1] };
        __builtin_nontemporal_store(a, (f2u*)(outr + OFF_D3 + 2 * t));
    }
    if (t < 6) {    // L3 tail: j = 1024..1029 from published cA2 (+reflection)
        const int jj = 1024 + t;
        float l = 0.f, h = 0.f;
#pragma unroll
        for (int j = 0; j < 8; ++j) {
            int g = 2 * jj - 6 + j;
            if (g > 2052) g = 4105 - g;        // reflect at N2
            float v = hB[(g & 3) * HS + (g >> 2)];
            l = fmaf(GLO[j], v, l);
            h = fmaf(GHI[j], v, h);
        }
        __builtin_nontemporal_store(h, outr + OFF_D3 + jj);
        hA[(jj & 1) * HS + (jj >> 1)] = l;
    }
    __syncthreads();

    // ---- L4: output j = t, taps w4[j'] where w4[k] = cA3[2t-6+k] ----
    float w4[8];
#pragma unroll
    for (int k = 0; k < 6; ++k) {
        int g = 2 * t - 6 + k;
        if (g < 0) g = -1 - g;
        w4[k] = hA[(g & 1) * HS + (g >> 1)];
    }
    w4[6] = lo3[0];
    w4[7] = lo3[1];
    {
        float l = 0.f, h = 0.f;
#pragma unroll
        for (int j = 0; j < 8; ++j) {
            float v = w4[j];
            l = fmaf(GLO[j], v, l);
            h = fmaf(GHI[j], v, h);
        }
        __builtin_nontemporal_store(l, outr + OFF_A4 + t);   // lane-consecutive
        __builtin_nontemporal_store(h, outr + OFF_D4 + t);
    }
    if (t < 6) {    // L4 tail: j = 512..517 from published cA3 (+reflection)
        const int jj = 512 + t;
        float l = 0.f, h = 0.f;
#pragma unroll
        for (int j = 0; j < 8; ++j) {
            int g = 2 * jj - 6 + j;
            if (g > 1029) g = 2059 - g;        // reflect at N3
            float v = hA[(g & 1) * HS + (g >> 1)];
            l = fmaf(GLO[j], v, l);
            h = fmaf(GHI[j], v, h);
        }
        __builtin_nontemporal_store(l, outr + OFF_A4 + jj);
        __builtin_nontemporal_store(h, outr + OFF_D4 + jj);
    }
}

extern "C" void kernel_launch(void* const* d_in, const int* in_sizes, int n_in,
                              void* d_out, int out_size, void* d_ws, size_t ws_size,
                              hipStream_t stream) {
    const float* x = (const float*)d_in[0];
    float* out = (float*)d_out;
    const int rows = in_sizes[0] / L0;  // 64*32 = 2048
    wavedec4_db4<<<dim3(rows), dim3(NT), 0, stream>>>(x, out);
}